// Round 1
// baseline (662.993 us; speedup 1.0000x reference)
//
#include <hip/hip_runtime.h>

#pragma clang fp contract(off)

// Problem constants (fixed by setup_inputs): B=32, G=50, H=W=64, A=9.
#define BB 32
#define GG 50
#define AA 9
#define HH 64
#define WW 64
#define KAT (HH*WW*AA)          // 36864 total anchors
#define NCAP 20480              // cap on inside-anchor count (actual = 18624)
#define MAXC 4096               // candidate list cap per image
#define NUMFG 128               // int(0.5 * 256)
#define RPNB 256
#define BG_T 0.05f              // bg priority pre-filter (256th smallest ~0.0143)
#define LAB_SZ (BB*AA*HH*WW)    // 1179648
#define REG_SZ (LAB_SZ*4)       // 4718592

// JAX >= 0.5 default: jax_threefry_partitionable = True. Flip to 0 if labels
// mismatch by +-1/+-2 (old-style threefry counter layout).
#define PARTITIONABLE 1

// Anchor (w,h) per type, order = ratios{0.5,1,2} x scales{8,16,32}
__constant__ float c_aw[9] = {184.f,368.f,736.f,128.f,256.f,512.f, 88.f,176.f,352.f};
__constant__ float c_ah[9] = { 96.f,192.f,384.f,128.f,256.f,512.f,176.f,352.f,704.f};

__device__ __forceinline__ unsigned rotl32(unsigned v, int d) {
  return (v << d) | (v >> (32 - d));
}

// Threefry-2x32, 20 rounds — matches jax._src.prng.threefry2x32
__device__ __forceinline__ void tf2x32(unsigned k0, unsigned k1,
                                       unsigned x0, unsigned x1,
                                       unsigned &o0, unsigned &o1) {
  unsigned ks2 = k0 ^ k1 ^ 0x1BD11BDAu;
  x0 += k0; x1 += k1;
#define TF_R(r) { x0 += x1; x1 = rotl32(x1, (r)); x1 ^= x0; }
  TF_R(13) TF_R(15) TF_R(26) TF_R(6)
  x0 += k1;  x1 += ks2 + 1u;
  TF_R(17) TF_R(29) TF_R(16) TF_R(24)
  x0 += ks2; x1 += k0 + 2u;
  TF_R(13) TF_R(15) TF_R(26) TF_R(6)
  x0 += k0;  x1 += k1 + 3u;
  TF_R(17) TF_R(29) TF_R(16) TF_R(24)
  x0 += k1;  x1 += ks2 + 4u;
  TF_R(13) TF_R(15) TF_R(26) TF_R(6)
  x0 += ks2; x1 += k0 + 5u;
#undef TF_R
  o0 = x0; o1 = x1;
}

__device__ __forceinline__ float bits_to_uniform(unsigned bits) {
  return __uint_as_float((bits >> 9) | 0x3f800000u) - 1.0f;
}

// uniform(key,(N,)) word i
__device__ __forceinline__ float pri_uniform(unsigned k0, unsigned k1, int i, int N) {
  unsigned o0, o1, bits;
#if PARTITIONABLE
  tf2x32(k0, k1, 0u, (unsigned)i, o0, o1);
  bits = o0 ^ o1;
#else
  int half = N >> 1;   // N is even (18624)
  if (i < half) { tf2x32(k0, k1, (unsigned)i, (unsigned)(i + half), o0, o1); bits = o0; }
  else          { tf2x32(k0, k1, (unsigned)(i - half), (unsigned)i, o0, o1); bits = o1; }
#endif
  return bits_to_uniform(bits);
}

__device__ __forceinline__ void anchor_box(int ka, int &a, int &x, int &y,
                                           float &ax1, float &ay1, float &ax2, float &ay2) {
  a = ka % AA; int pos = ka / AA; x = pos & (WW - 1); y = pos >> 6;
  float hw = 0.5f * (c_aw[a] - 1.0f);
  float hh = 0.5f * (c_ah[a] - 1.0f);
  float cx = (float)(16 * x) + 7.5f;
  float cy = (float)(16 * y) + 7.5f;
  ax1 = cx - hw; ay1 = cy - hh; ax2 = cx + hw; ay2 = cy + hh;
}

// IoU with +1 convention, op order exactly as reference (no FMA: contract off)
__device__ __forceinline__ float iou_f(float ax1, float ay1, float ax2, float ay2,
                                       float gx1, float gy1, float gx2, float gy2) {
  float area_a = ((ax2 - ax1) + 1.0f) * ((ay2 - ay1) + 1.0f);
  float area_g = ((gx2 - gx1) + 1.0f) * ((gy2 - gy1) + 1.0f);
  float iw = (fminf(ax2, gx2) - fmaxf(ax1, gx1)) + 1.0f; iw = fmaxf(iw, 0.0f);
  float ih = (fminf(ay2, gy2) - fmaxf(ay1, gy1)) + 1.0f; ih = fmaxf(ih, 0.0f);
  float inter = iw * ih;
  return inter / ((area_a + area_g) - inter);
}

// ---- K0: zero counters + derive per-image kf/kb keys --------------------
__global__ void k_init(unsigned* keyf, unsigned* keyb, int* fg_cnt, int* bg_cnt) {
  int b = threadIdx.x;
  if (b >= BB) return;
  fg_cnt[b] = 0; bg_cnt[b] = 0;
#if PARTITIONABLE
  unsigned h, l, f0, f1, g0, g1;
  tf2x32(0u, 42u, 0u, (unsigned)b, h, l);      // split(key(42),32)[b]  (foldlike)
  tf2x32(h, l, 0u, 0u, f0, f1);                // split(key_b)[0] = kf
  tf2x32(h, l, 0u, 1u, g0, g1);                // split(key_b)[1] = kb
  keyf[2*b] = f0; keyf[2*b+1] = f1;
  keyb[2*b] = g0; keyb[2*b+1] = g1;
#else
  // original split: counts=iota(64), pairs (j, j+32)
  unsigned r0, r1, h, l;
  int j0 = 2 * b, j1 = 2 * b + 1;
  if (j0 < 32) { tf2x32(0u, 42u, (unsigned)j0, (unsigned)(j0 + 32), r0, r1); h = r0; }
  else         { tf2x32(0u, 42u, (unsigned)(j0 - 32), (unsigned)j0, r0, r1); h = r1; }
  if (j1 < 32) { tf2x32(0u, 42u, (unsigned)j1, (unsigned)(j1 + 32), r0, r1); l = r0; }
  else         { tf2x32(0u, 42u, (unsigned)(j1 - 32), (unsigned)j1, r0, r1); l = r1; }
  unsigned w0, w1, w2, w3;
  tf2x32(h, l, 0u, 2u, w0, w2);                // counts iota(4): pairs (0,2),(1,3)
  tf2x32(h, l, 1u, 3u, w1, w3);
  keyf[2*b] = w0; keyf[2*b+1] = w1;
  keyb[2*b] = w2; keyb[2*b+1] = w3;
#endif
}

// ---- K1: compact inside-anchor list (single block, ballot scan) ---------
__global__ void k_compact(int* inside, int* dN) {
  __shared__ int wsum[4];
  __shared__ int base_s;
  if (threadIdx.x == 0) base_s = 0;
  __syncthreads();
  for (int start = 0; start < KAT; start += 256) {
    int ka = start + threadIdx.x;
    int a, x, y; float ax1, ay1, ax2, ay2;
    anchor_box(ka, a, x, y, ax1, ay1, ax2, ay2);
    bool m = (ax1 >= 0.0f) && (ay1 >= 0.0f) && (ax2 < 1024.0f) && (ay2 < 1024.0f);
    unsigned long long bal = __ballot(m);
    int lane = threadIdx.x & 63, wv = threadIdx.x >> 6;
    if (lane == 0) wsum[wv] = __popcll(bal);
    __syncthreads();
    int woff = 0;
    for (int w = 0; w < wv; ++w) woff += wsum[w];
    int tot = wsum[0] + wsum[1] + wsum[2] + wsum[3];
    int pos = base_s + woff + __popcll(bal & ((1ull << lane) - 1ull));
    if (m && pos < NCAP) inside[pos] = ka;
    __syncthreads();
    if (threadIdx.x == 0) base_s += tot;
    __syncthreads();
  }
  if (threadIdx.x == 0) *dN = base_s;
}

// ---- K2: per-(b,g) max IoU over all inside anchors ----------------------
__global__ void k_gtmax(const float* __restrict__ gt, const int* __restrict__ inside,
                        const int* __restrict__ dN, float* __restrict__ gt_max) {
  int bg = blockIdx.x;           // 0..B*G-1
  int b = bg / GG, g = bg % GG;
  const float* gr = gt + (b * GG + g) * 4;
  float gx1 = gr[0], gy1 = gr[1], gx2 = gr[2], gy2 = gr[3];
  int N = min(*dN, NCAP);
  float best = -1.0f;
  for (int i = threadIdx.x; i < N; i += 64) {
    int ka = inside[i];
    int a, x, y; float ax1, ay1, ax2, ay2;
    anchor_box(ka, a, x, y, ax1, ay1, ax2, ay2);
    best = fmaxf(best, iou_f(ax1, ay1, ax2, ay2, gx1, gy1, gx2, gy2));
  }
  for (int off = 32; off > 0; off >>= 1)
    best = fmaxf(best, __shfl_down(best, off));
  if (threadIdx.x == 0) gt_max[b * GG + g] = best;
}

// ---- K3: labels, argmax, priorities, candidate lists --------------------
__global__ void k_labels(const float* __restrict__ gt, const int* __restrict__ inside,
                         const int* __restrict__ dN, const float* __restrict__ gt_max,
                         const unsigned* __restrict__ keyf, const unsigned* __restrict__ keyb,
                         signed char* __restrict__ lab, unsigned char* __restrict__ am,
                         int* fg_cnt, int* fg_idx, float* fg_pri,
                         int* bg_cnt, int* bg_idx, float* bg_pri) {
  __shared__ float sg[GG * 4];
  __shared__ float sm[GG];
  int b = blockIdx.y;
  int i = blockIdx.x * 256 + threadIdx.x;
  for (int t = threadIdx.x; t < GG * 4; t += 256) sg[t] = gt[b * GG * 4 + t];
  for (int t = threadIdx.x; t < GG; t += 256) sm[t] = gt_max[b * GG + t];
  __syncthreads();
  int N = min(*dN, NCAP);
  if (i >= N) return;
  int ka = inside[i];
  int a, x, y; float ax1, ay1, ax2, ay2;
  anchor_box(ka, a, x, y, ax1, ay1, ax2, ay2);
  float best = -1.0f; int argg = 0; bool hit = false;
  for (int g = 0; g < GG; ++g) {
    float ov = iou_f(ax1, ay1, ax2, ay2,
                     sg[g*4+0], sg[g*4+1], sg[g*4+2], sg[g*4+3]);
    if (ov > best) { best = ov; argg = g; }   // argmax: first occurrence wins
    hit = hit || ((ov == sm[g]) && (sm[g] > 0.0f));
  }
  int label = (hit || best >= 0.7f) ? 1 : ((best < 0.3f) ? 0 : -1);
  lab[b * NCAP + i] = (signed char)label;
  am[b * NCAP + i]  = (unsigned char)argg;
  if (label == 1) {
    float p = pri_uniform(keyf[2*b], keyf[2*b+1], i, N);
    int c = atomicAdd(&fg_cnt[b], 1);
    if (c < MAXC) { fg_idx[b * MAXC + c] = i; fg_pri[b * MAXC + c] = p; }
  } else if (label == 0) {
    float p = pri_uniform(keyb[2*b], keyb[2*b+1], i, N);
    if (p < BG_T) {
      int c = atomicAdd(&bg_cnt[b], 1);
      if (c < MAXC) { bg_idx[b * MAXC + c] = i; bg_pri[b * MAXC + c] = p; }
    }
  }
}

// ---- K4: fg subsample (exact rank by (pri, idx) = stable argsort) -------
__global__ void k_select_fg(const int* __restrict__ fg_cnt, const int* __restrict__ fg_idx,
                            const float* __restrict__ fg_pri, signed char* __restrict__ lab) {
  int b = blockIdx.x;
  int F = min(fg_cnt[b], MAXC);
  if (F <= NUMFG) return;      // all fg kept
  for (int c = threadIdx.x; c < F; c += blockDim.x) {
    int i = fg_idx[b * MAXC + c];
    float p = fg_pri[b * MAXC + c];
    int rank = 0;
    for (int j = 0; j < F; ++j) {
      float q = fg_pri[b * MAXC + j];
      int ij = fg_idx[b * MAXC + j];
      rank += (q < p || (q == p && ij < i)) ? 1 : 0;
    }
    if (rank >= NUMFG) lab[b * NCAP + i] = -1;   // demote
  }
}

// ---- K5: bg subsample; kept bg marked with sentinel 2 -------------------
__global__ void k_select_bg(const int* __restrict__ fg_cnt, const int* __restrict__ bg_cnt,
                            const int* __restrict__ bg_idx, const float* __restrict__ bg_pri,
                            signed char* __restrict__ lab) {
  int b = blockIdx.x;
  int nk = RPNB - min(fg_cnt[b], NUMFG);   // num_bg = 256 - kept_fg
  int C = min(bg_cnt[b], MAXC);
  for (int c = threadIdx.x; c < C; c += blockDim.x) {
    int i = bg_idx[b * MAXC + c];
    float p = bg_pri[b * MAXC + c];
    int rank = 0;
    for (int j = 0; j < C; ++j) {
      float q = bg_pri[b * MAXC + j];
      rank += (q < p || (q == p && bg_idx[b * MAXC + j] < i)) ? 1 : 0;
    }
    if (rank < nk) lab[b * NCAP + i] = 2;    // kept bg
  }
}

// ---- K6: fill output defaults (labels=-1, reg=0) ------------------------
__global__ void k_fill(float* __restrict__ out) {
  int idx = blockIdx.x * 256 + threadIdx.x;
  if (idx < LAB_SZ) out[idx] = -1.0f;
  else if (idx < LAB_SZ + REG_SZ) out[idx] = 0.0f;
}

// ---- K7: scatter labels + bbox_transform regs ---------------------------
__global__ void k_scatter(const float* __restrict__ gt, const int* __restrict__ inside,
                          const int* __restrict__ dN, const signed char* __restrict__ lab,
                          const unsigned char* __restrict__ am, float* __restrict__ out) {
  int b = blockIdx.y;
  int i = blockIdx.x * 256 + threadIdx.x;
  int N = min(*dN, NCAP);
  if (i >= N) return;
  int ka = inside[i];
  int a, x, y; float ax1, ay1, ax2, ay2;
  anchor_box(ka, a, x, y, ax1, ay1, ax2, ay2);
  signed char v = lab[b * NCAP + i];
  float lv = (v == 1) ? 1.0f : ((v == 2) ? 0.0f : -1.0f);
  out[b * (AA*HH*WW) + a * (HH*WW) + y * WW + x] = lv;
  if (v == 1) {
    int g = am[b * NCAP + i];
    const float* gr = gt + (b * GG + g) * 4;
    float gx1 = gr[0], gy1 = gr[1], gx2 = gr[2], gy2 = gr[3];
    float aw = (ax2 - ax1) + 1.0f, ah = (ay2 - ay1) + 1.0f;
    float acx = ax1 + 0.5f * (aw - 1.0f), acy = ay1 + 0.5f * (ah - 1.0f);
    float gw = (gx2 - gx1) + 1.0f, gh = (gy2 - gy1) + 1.0f;
    float gcx = gx1 + 0.5f * (gw - 1.0f), gcy = gy1 + 0.5f * (gh - 1.0f);
    float t0 = (gcx - acx) / aw;
    float t1 = (gcy - acy) / ah;
    float t2 = logf(gw / aw);
    float t3 = logf(gh / ah);
    float* rb = out + LAB_SZ + b * (4*AA*HH*WW) + (a * 4) * (HH*WW) + y * WW + x;
    rb[0*HH*WW] = t0; rb[1*HH*WW] = t1; rb[2*HH*WW] = t2; rb[3*HH*WW] = t3;
  }
}

extern "C" void kernel_launch(void* const* d_in, const int* in_sizes, int n_in,
                              void* d_out, int out_size, void* d_ws, size_t ws_size,
                              hipStream_t stream) {
  const float* gt = (const float*)d_in[0];
  float* out = (float*)d_out;

  char* w = (char*)d_ws;
  int* dN          = (int*)w;            w += 256;
  int* fg_cnt      = (int*)w;            w += 256;
  int* bg_cnt      = (int*)w;            w += 256;
  unsigned* keyf   = (unsigned*)w;       w += 256;
  unsigned* keyb   = (unsigned*)w;       w += 256;
  float* gt_max    = (float*)w;          w += BB*GG*sizeof(float);    // 6400
  int* inside      = (int*)w;            w += KAT*sizeof(int);        // 147456
  signed char* lab = (signed char*)w;    w += BB*NCAP;                // 655360
  unsigned char* am= (unsigned char*)w;  w += BB*NCAP;                // 655360
  int* fg_idx      = (int*)w;            w += BB*MAXC*sizeof(int);
  float* fg_pri    = (float*)w;          w += BB*MAXC*sizeof(float);
  int* bg_idx      = (int*)w;            w += BB*MAXC*sizeof(int);
  float* bg_pri    = (float*)w;          w += BB*MAXC*sizeof(float);
  // total ~3.6 MB of d_ws

  k_init<<<1, 32, 0, stream>>>(keyf, keyb, fg_cnt, bg_cnt);
  k_compact<<<1, 256, 0, stream>>>(inside, dN);
  k_gtmax<<<BB*GG, 64, 0, stream>>>(gt, inside, dN, gt_max);
  k_labels<<<dim3(NCAP/256, BB), 256, 0, stream>>>(gt, inside, dN, gt_max, keyf, keyb,
                                                   lab, am, fg_cnt, fg_idx, fg_pri,
                                                   bg_cnt, bg_idx, bg_pri);
  k_select_fg<<<BB, 256, 0, stream>>>(fg_cnt, fg_idx, fg_pri, lab);
  k_select_bg<<<BB, 256, 0, stream>>>(fg_cnt, bg_cnt, bg_idx, bg_pri, lab);
  k_fill<<<(LAB_SZ + REG_SZ) / 256, 256, 0, stream>>>(out);
  k_scatter<<<dim3(NCAP/256, BB), 256, 0, stream>>>(gt, inside, dN, lab, am, out);
}

// Round 2
// 347.821 us; speedup vs baseline: 1.9061x; 1.9061x over previous
//
#include <hip/hip_runtime.h>

#pragma clang fp contract(off)

// Problem constants (fixed by setup_inputs): B=32, G=50, H=W=64, A=9.
#define BB 32
#define GG 50
#define AA 9
#define HH 64
#define WW 64
#define KAT (HH*WW*AA)          // 36864 total anchors
#define NCAP 20480              // cap on inside-anchor count (actual = 18624)
#define MAXC 4096               // candidate list cap per image
#define NUMFG 128               // int(0.5 * 256)
#define RPNB 256
#define BG_T 0.05f              // bg priority pre-filter (256th smallest ~0.0143)
#define LAB_SZ (BB*AA*HH*WW)    // 1179648
#define REG_SZ (LAB_SZ*4)       // 4718592

// JAX >= 0.5 default: jax_threefry_partitionable = True (verified: passed R1).
#define PARTITIONABLE 1

// Anchor (w,h) per type, order = ratios{0.5,1,2} x scales{8,16,32}
__constant__ float c_aw[9] = {184.f,368.f,736.f,128.f,256.f,512.f, 88.f,176.f,352.f};
__constant__ float c_ah[9] = { 96.f,192.f,384.f,128.f,256.f,512.f,176.f,352.f,704.f};

__device__ __forceinline__ unsigned rotl32(unsigned v, int d) {
  return (v << d) | (v >> (32 - d));
}

// Threefry-2x32, 20 rounds — matches jax._src.prng.threefry2x32
__device__ __forceinline__ void tf2x32(unsigned k0, unsigned k1,
                                       unsigned x0, unsigned x1,
                                       unsigned &o0, unsigned &o1) {
  unsigned ks2 = k0 ^ k1 ^ 0x1BD11BDAu;
  x0 += k0; x1 += k1;
#define TF_R(r) { x0 += x1; x1 = rotl32(x1, (r)); x1 ^= x0; }
  TF_R(13) TF_R(15) TF_R(26) TF_R(6)
  x0 += k1;  x1 += ks2 + 1u;
  TF_R(17) TF_R(29) TF_R(16) TF_R(24)
  x0 += ks2; x1 += k0 + 2u;
  TF_R(13) TF_R(15) TF_R(26) TF_R(6)
  x0 += k0;  x1 += k1 + 3u;
  TF_R(17) TF_R(29) TF_R(16) TF_R(24)
  x0 += k1;  x1 += ks2 + 4u;
  TF_R(13) TF_R(15) TF_R(26) TF_R(6)
  x0 += ks2; x1 += k0 + 5u;
#undef TF_R
  o0 = x0; o1 = x1;
}

__device__ __forceinline__ float bits_to_uniform(unsigned bits) {
  return __uint_as_float((bits >> 9) | 0x3f800000u) - 1.0f;
}

// uniform(key,(N,)) word i
__device__ __forceinline__ float pri_uniform(unsigned k0, unsigned k1, int i, int N) {
  unsigned o0, o1, bits;
#if PARTITIONABLE
  tf2x32(k0, k1, 0u, (unsigned)i, o0, o1);
  bits = o0 ^ o1;
#else
  int half = N >> 1;
  if (i < half) { tf2x32(k0, k1, (unsigned)i, (unsigned)(i + half), o0, o1); bits = o0; }
  else          { tf2x32(k0, k1, (unsigned)(i - half), (unsigned)i, o0, o1); bits = o1; }
#endif
  return bits_to_uniform(bits);
}

__device__ __forceinline__ void box_from_ayx(int a, int x, int y,
                                             float &ax1, float &ay1, float &ax2, float &ay2) {
  float hw = 0.5f * (c_aw[a] - 1.0f);
  float hh = 0.5f * (c_ah[a] - 1.0f);
  float cx = (float)(16 * x) + 7.5f;
  float cy = (float)(16 * y) + 7.5f;
  ax1 = cx - hw; ay1 = cy - hh; ax2 = cx + hw; ay2 = cy + hh;
}

__device__ __forceinline__ void anchor_box(int ka, int &a, int &x, int &y,
                                           float &ax1, float &ay1, float &ax2, float &ay2) {
  a = ka % AA; int pos = ka / AA; x = pos & (WW - 1); y = pos >> 6;
  box_from_ayx(a, x, y, ax1, ay1, ax2, ay2);
}

// IoU with +1 convention, op order exactly as reference (no FMA: contract off)
__device__ __forceinline__ float iou_f(float ax1, float ay1, float ax2, float ay2,
                                       float gx1, float gy1, float gx2, float gy2) {
  float area_a = ((ax2 - ax1) + 1.0f) * ((ay2 - ay1) + 1.0f);
  float area_g = ((gx2 - gx1) + 1.0f) * ((gy2 - gy1) + 1.0f);
  float iw = (fminf(ax2, gx2) - fmaxf(ax1, gx1)) + 1.0f; iw = fmaxf(iw, 0.0f);
  float ih = (fminf(ay2, gy2) - fmaxf(ay1, gy1)) + 1.0f; ih = fmaxf(ih, 0.0f);
  float inter = iw * ih;
  return inter / ((area_a + area_g) - inter);
}

// ---- K1: init keys/counters + compact inside list + inverse map ---------
__global__ void k_compact(int* inside, int* inv, int* dN,
                          unsigned* keyf, unsigned* keyb, int* fg_cnt, int* bg_cnt) {
  // init section (wave 0, lanes 0..31)
  if (threadIdx.x < BB) {
    int b = threadIdx.x;
    fg_cnt[b] = 0; bg_cnt[b] = 0;
    unsigned h, l, f0, f1, g0, g1;
    tf2x32(0u, 42u, 0u, (unsigned)b, h, l);      // split(key(42),32)[b]
    tf2x32(h, l, 0u, 0u, f0, f1);                // kf
    tf2x32(h, l, 0u, 1u, g0, g1);                // kb
    keyf[2*b] = f0; keyf[2*b+1] = f1;
    keyb[2*b] = g0; keyb[2*b+1] = g1;
  }
  __shared__ int wsum[4];
  __shared__ int base_s;
  if (threadIdx.x == 0) base_s = 0;
  __syncthreads();
  for (int start = 0; start < KAT; start += 256) {
    int ka = start + threadIdx.x;
    int a, x, y; float ax1, ay1, ax2, ay2;
    anchor_box(ka, a, x, y, ax1, ay1, ax2, ay2);
    bool m = (ax1 >= 0.0f) && (ay1 >= 0.0f) && (ax2 < 1024.0f) && (ay2 < 1024.0f);
    unsigned long long bal = __ballot(m);
    int lane = threadIdx.x & 63, wv = threadIdx.x >> 6;
    if (lane == 0) wsum[wv] = __popcll(bal);
    __syncthreads();
    int woff = 0;
    for (int w = 0; w < wv; ++w) woff += wsum[w];
    int tot = wsum[0] + wsum[1] + wsum[2] + wsum[3];
    int pos = base_s + woff + __popcll(bal & ((1ull << lane) - 1ull));
    bool ok = m && pos < NCAP;
    if (ok) inside[pos] = ka;
    inv[ka] = ok ? pos : -1;
    __syncthreads();
    if (threadIdx.x == 0) base_s += tot;
    __syncthreads();
  }
  if (threadIdx.x == 0) *dN = base_s;
}

// ---- K2: per-(b,g) max IoU over all inside anchors ----------------------
__global__ void k_gtmax(const float* __restrict__ gt, const int* __restrict__ inside,
                        const int* __restrict__ dN, float* __restrict__ gt_max) {
  int bg = blockIdx.x;           // 0..B*G-1
  int b = bg / GG, g = bg % GG;
  const float* gr = gt + (b * GG + g) * 4;
  float gx1 = gr[0], gy1 = gr[1], gx2 = gr[2], gy2 = gr[3];
  int N = min(*dN, NCAP);
  float best = -1.0f;
  for (int i = threadIdx.x; i < N; i += 64) {
    int ka = inside[i];
    int a, x, y; float ax1, ay1, ax2, ay2;
    anchor_box(ka, a, x, y, ax1, ay1, ax2, ay2);
    best = fmaxf(best, iou_f(ax1, ay1, ax2, ay2, gx1, gy1, gx2, gy2));
  }
  for (int off = 32; off > 0; off >>= 1)
    best = fmaxf(best, __shfl_down(best, off));
  if (threadIdx.x == 0) gt_max[b * GG + g] = best;
}

// ---- K3: labels, argmax, priorities, candidate lists --------------------
__global__ void k_labels(const float* __restrict__ gt, const int* __restrict__ inside,
                         const int* __restrict__ dN, const float* __restrict__ gt_max,
                         const unsigned* __restrict__ keyf, const unsigned* __restrict__ keyb,
                         signed char* __restrict__ lab, unsigned char* __restrict__ am,
                         int* fg_cnt, int* fg_idx, float* fg_pri,
                         int* bg_cnt, int* bg_idx, float* bg_pri) {
  __shared__ float sg[GG * 4];
  __shared__ float sm[GG];
  int b = blockIdx.y;
  int i = blockIdx.x * 256 + threadIdx.x;
  for (int t = threadIdx.x; t < GG * 4; t += 256) sg[t] = gt[b * GG * 4 + t];
  for (int t = threadIdx.x; t < GG; t += 256) sm[t] = gt_max[b * GG + t];
  __syncthreads();
  int N = min(*dN, NCAP);
  if (i >= N) return;
  int ka = inside[i];
  int a, x, y; float ax1, ay1, ax2, ay2;
  anchor_box(ka, a, x, y, ax1, ay1, ax2, ay2);
  float best = -1.0f; int argg = 0; bool hit = false;
  for (int g = 0; g < GG; ++g) {
    float ov = iou_f(ax1, ay1, ax2, ay2,
                     sg[g*4+0], sg[g*4+1], sg[g*4+2], sg[g*4+3]);
    if (ov > best) { best = ov; argg = g; }   // argmax: first occurrence wins
    hit = hit || ((ov == sm[g]) && (sm[g] > 0.0f));
  }
  int label = (hit || best >= 0.7f) ? 1 : ((best < 0.3f) ? 0 : -1);
  lab[b * NCAP + i] = (signed char)label;
  am[b * NCAP + i]  = (unsigned char)argg;
  if (label == 1) {
    float p = pri_uniform(keyf[2*b], keyf[2*b+1], i, N);
    int c = atomicAdd(&fg_cnt[b], 1);
    if (c < MAXC) { fg_idx[b * MAXC + c] = i; fg_pri[b * MAXC + c] = p; }
  } else if (label == 0) {
    float p = pri_uniform(keyb[2*b], keyb[2*b+1], i, N);
    if (p < BG_T) {
      int c = atomicAdd(&bg_cnt[b], 1);
      if (c < MAXC) { bg_idx[b * MAXC + c] = i; bg_pri[b * MAXC + c] = p; }
    }
  }
}

// Packed (pri,idx) key: pri >= 0 so float bit-pattern preserves order as u32;
// low 32 bits = compact index -> u64 '<' reproduces stable-argsort tie-break.
__device__ __forceinline__ unsigned long long pack_key(float p, int i) {
  return ((unsigned long long)__float_as_uint(p) << 32) | (unsigned)i;
}

// ---- K4: fg subsample via LDS rank-select -------------------------------
__global__ void k_select_fg(const int* __restrict__ fg_cnt, const int* __restrict__ fg_idx,
                            const float* __restrict__ fg_pri, signed char* __restrict__ lab) {
  __shared__ unsigned long long sk[MAXC];
  int b = blockIdx.x;
  int F = min(fg_cnt[b], MAXC);
  if (F <= NUMFG) return;      // all fg kept
  for (int c = threadIdx.x; c < F; c += blockDim.x)
    sk[c] = pack_key(fg_pri[b * MAXC + c], fg_idx[b * MAXC + c]);
  __syncthreads();
  for (int c = threadIdx.x; c < F; c += blockDim.x) {
    unsigned long long me = sk[c];
    int rank = 0;
    for (int j = 0; j < F; ++j) rank += (sk[j] < me) ? 1 : 0;
    if (rank >= NUMFG) lab[b * NCAP + (int)(me & 0xFFFFFFFFu)] = -1;  // demote
  }
}

// ---- K5: bg subsample via LDS rank-select; kept bg marked 2 -------------
__global__ void k_select_bg(const int* __restrict__ fg_cnt, const int* __restrict__ bg_cnt,
                            const int* __restrict__ bg_idx, const float* __restrict__ bg_pri,
                            signed char* __restrict__ lab) {
  __shared__ unsigned long long sk[MAXC];
  int b = blockIdx.x;
  int nk = RPNB - min(fg_cnt[b], NUMFG);   // num_bg = 256 - kept_fg
  int C = min(bg_cnt[b], MAXC);
  for (int c = threadIdx.x; c < C; c += blockDim.x)
    sk[c] = pack_key(bg_pri[b * MAXC + c], bg_idx[b * MAXC + c]);
  __syncthreads();
  for (int c = threadIdx.x; c < C; c += blockDim.x) {
    unsigned long long me = sk[c];
    int rank = 0;
    for (int j = 0; j < C; ++j) rank += (sk[j] < me) ? 1 : 0;
    if (rank < nk) lab[b * NCAP + (int)(me & 0xFFFFFFFFu)] = 2;    // kept bg
  }
}

// ---- K6: merged fill+scatter, output-ordered, fully coalesced -----------
__global__ void k_out(const float* __restrict__ gt, const int* __restrict__ inv,
                      const signed char* __restrict__ lab, const unsigned char* __restrict__ am,
                      float* __restrict__ out) {
  int b = blockIdx.y;
  int t = blockIdx.x * 256 + threadIdx.x;   // t = a*4096 + y*64 + x  (output order)
  int a = t >> 12, pos = t & 4095;
  int ka = pos * AA + a;
  int i = inv[ka];
  float lv = -1.0f, t0 = 0.f, t1 = 0.f, t2 = 0.f, t3 = 0.f;
  if (i >= 0) {
    signed char v = lab[b * NCAP + i];
    lv = (v == 1) ? 1.0f : ((v == 2) ? 0.0f : -1.0f);
    if (v == 1) {
      int y = pos >> 6, x = pos & 63;
      float ax1, ay1, ax2, ay2;
      box_from_ayx(a, x, y, ax1, ay1, ax2, ay2);
      int g = am[b * NCAP + i];
      const float* gr = gt + (b * GG + g) * 4;
      float gx1 = gr[0], gy1 = gr[1], gx2 = gr[2], gy2 = gr[3];
      float aw = (ax2 - ax1) + 1.0f, ah = (ay2 - ay1) + 1.0f;
      float acx = ax1 + 0.5f * (aw - 1.0f), acy = ay1 + 0.5f * (ah - 1.0f);
      float gw = (gx2 - gx1) + 1.0f, gh = (gy2 - gy1) + 1.0f;
      float gcx = gx1 + 0.5f * (gw - 1.0f), gcy = gy1 + 0.5f * (gh - 1.0f);
      t0 = (gcx - acx) / aw;
      t1 = (gcy - acy) / ah;
      t2 = logf(gw / aw);
      t3 = logf(gh / ah);
    }
  }
  out[b * KAT + t] = lv;
  float* rb = out + LAB_SZ + b * (4 * KAT) + (a * 4) * 4096 + pos;
  rb[0] = t0; rb[4096] = t1; rb[2 * 4096] = t2; rb[3 * 4096] = t3;
}

extern "C" void kernel_launch(void* const* d_in, const int* in_sizes, int n_in,
                              void* d_out, int out_size, void* d_ws, size_t ws_size,
                              hipStream_t stream) {
  const float* gt = (const float*)d_in[0];
  float* out = (float*)d_out;

  char* w = (char*)d_ws;
  int* dN          = (int*)w;            w += 256;
  int* fg_cnt      = (int*)w;            w += 256;
  int* bg_cnt      = (int*)w;            w += 256;
  unsigned* keyf   = (unsigned*)w;       w += 256;
  unsigned* keyb   = (unsigned*)w;       w += 256;
  float* gt_max    = (float*)w;          w += BB*GG*sizeof(float);    // 6400
  int* inside      = (int*)w;            w += KAT*sizeof(int);        // 147456
  int* inv         = (int*)w;            w += KAT*sizeof(int);        // 147456
  signed char* lab = (signed char*)w;    w += BB*NCAP;                // 655360
  unsigned char* am= (unsigned char*)w;  w += BB*NCAP;                // 655360
  int* fg_idx      = (int*)w;            w += BB*MAXC*sizeof(int);
  float* fg_pri    = (float*)w;          w += BB*MAXC*sizeof(float);
  int* bg_idx      = (int*)w;            w += BB*MAXC*sizeof(int);
  float* bg_pri    = (float*)w;          w += BB*MAXC*sizeof(float);
  // total ~3.8 MB of d_ws

  k_compact<<<1, 256, 0, stream>>>(inside, inv, dN, keyf, keyb, fg_cnt, bg_cnt);
  k_gtmax<<<BB*GG, 64, 0, stream>>>(gt, inside, dN, gt_max);
  k_labels<<<dim3(NCAP/256, BB), 256, 0, stream>>>(gt, inside, dN, gt_max, keyf, keyb,
                                                   lab, am, fg_cnt, fg_idx, fg_pri,
                                                   bg_cnt, bg_idx, bg_pri);
  k_select_fg<<<BB, 256, 0, stream>>>(fg_cnt, fg_idx, fg_pri, lab);
  k_select_bg<<<BB, 1024, 0, stream>>>(fg_cnt, bg_cnt, bg_idx, bg_pri, lab);
  k_out<<<dim3(KAT/256, BB), 256, 0, stream>>>(gt, inv, lab, am, out);
}

// Round 3
// 225.339 us; speedup vs baseline: 2.9422x; 1.5435x over previous
//
#include <hip/hip_runtime.h>

#pragma clang fp contract(off)

// Problem constants (fixed by setup_inputs): B=32, G=50, H=W=64, A=9.
#define BB 32
#define GG 50
#define AA 9
#define HH 64
#define WW 64
#define KAT (HH*WW*AA)          // 36864 total anchors
#define NCAP 20480              // cap on inside-anchor count (actual = 18624)
#define MAXC 4096               // candidate list cap per image
#define NUMFG 128               // int(0.5 * 256)
#define RPNB 256
#define BG_T 0.05f              // bg priority pre-filter (256th smallest ~0.0143)
#define LAB_SZ (BB*AA*HH*WW)    // 1179648
#define REG_SZ (LAB_SZ*4)       // 4718592
#define ANPT 4                  // anchors per thread in k_labels
#define GCH 5                   // gts per block in k_gtmax

// Anchor (w,h) per type, order = ratios{0.5,1,2} x scales{8,16,32}
__constant__ float c_aw[9] = {184.f,368.f,736.f,128.f,256.f,512.f, 88.f,176.f,352.f};
__constant__ float c_ah[9] = { 96.f,192.f,384.f,128.f,256.f,512.f,176.f,352.f,704.f};
__constant__ int   c_awi[9] = {184,368,736,128,256,512, 88,176,352};
__constant__ int   c_ahi[9] = { 96,192,384,128,256,512,176,352,704};

__device__ __forceinline__ unsigned rotl32(unsigned v, int d) {
  return (v << d) | (v >> (32 - d));
}

// Threefry-2x32, 20 rounds — matches jax._src.prng.threefry2x32
__device__ __forceinline__ void tf2x32(unsigned k0, unsigned k1,
                                       unsigned x0, unsigned x1,
                                       unsigned &o0, unsigned &o1) {
  unsigned ks2 = k0 ^ k1 ^ 0x1BD11BDAu;
  x0 += k0; x1 += k1;
#define TF_R(r) { x0 += x1; x1 = rotl32(x1, (r)); x1 ^= x0; }
  TF_R(13) TF_R(15) TF_R(26) TF_R(6)
  x0 += k1;  x1 += ks2 + 1u;
  TF_R(17) TF_R(29) TF_R(16) TF_R(24)
  x0 += ks2; x1 += k0 + 2u;
  TF_R(13) TF_R(15) TF_R(26) TF_R(6)
  x0 += k0;  x1 += k1 + 3u;
  TF_R(17) TF_R(29) TF_R(16) TF_R(24)
  x0 += k1;  x1 += ks2 + 4u;
  TF_R(13) TF_R(15) TF_R(26) TF_R(6)
  x0 += ks2; x1 += k0 + 5u;
#undef TF_R
  o0 = x0; o1 = x1;
}

__device__ __forceinline__ float bits_to_uniform(unsigned bits) {
  return __uint_as_float((bits >> 9) | 0x3f800000u) - 1.0f;
}

// uniform(key,(N,)) word i — jax_threefry_partitionable=True path (verified R1)
__device__ __forceinline__ float pri_uniform(unsigned k0, unsigned k1, int i) {
  unsigned o0, o1;
  tf2x32(k0, k1, 0u, (unsigned)i, o0, o1);
  return bits_to_uniform(o0 ^ o1);
}

__device__ __forceinline__ void box_from_ayx(int a, int x, int y,
                                             float &ax1, float &ay1, float &ax2, float &ay2) {
  float hw = 0.5f * (c_aw[a] - 1.0f);
  float hh = 0.5f * (c_ah[a] - 1.0f);
  float cx = (float)(16 * x) + 7.5f;
  float cy = (float)(16 * y) + 7.5f;
  ax1 = cx - hw; ay1 = cy - hh; ax2 = cx + hw; ay2 = cy + hh;
}

__device__ __forceinline__ void anchor_box(int ka, int &a, int &x, int &y,
                                           float &ax1, float &ay1, float &ax2, float &ay2) {
  a = ka % AA; int pos = ka / AA; x = pos & (WW - 1); y = pos >> 6;
  box_from_ayx(a, x, y, ax1, ay1, ax2, ay2);
}

// IoU core with precomputed areas; op order exactly as reference (contract off).
__device__ __forceinline__ float iou_pre(float ax1, float ay1, float ax2, float ay2, float area_a,
                                         float gx1, float gy1, float gx2, float gy2, float area_g) {
  float iw = (fminf(ax2, gx2) - fmaxf(ax1, gx1)) + 1.0f; iw = fmaxf(iw, 0.0f);
  float ih = (fminf(ay2, gy2) - fmaxf(ay1, gy1)) + 1.0f; ih = fmaxf(ih, 0.0f);
  float inter = iw * ih;
  return inter / ((area_a + area_g) - inter);
}

// ---- K1: analytic compact (no scan) + key/counter init ------------------
// Anchor-box float math is exact (multiples of 0.5 < 2048), so the inside
// test reduces to integer ranges: x in [(hw2+16)>>5, (2032-hw2)>>5],
// hw2 = w-1 (== 2*hw). Each thread computes its global prefix analytically.
__global__ void k_prep(int* __restrict__ inside, int* __restrict__ inv, int* __restrict__ dN,
                       unsigned* __restrict__ keyf, unsigned* __restrict__ keyb,
                       int* __restrict__ fg_cnt, int* __restrict__ bg_cnt) {
  if (blockIdx.x == 0 && threadIdx.x < BB) {
    int b = threadIdx.x;
    fg_cnt[b] = 0; bg_cnt[b] = 0;
    unsigned h, l, f0, f1, g0, g1;
    tf2x32(0u, 42u, 0u, (unsigned)b, h, l);      // split(key(42),32)[b]
    tf2x32(h, l, 0u, 0u, f0, f1);                // kf
    tf2x32(h, l, 0u, 1u, g0, g1);                // kb
    keyf[2*b] = f0; keyf[2*b+1] = f1;
    keyb[2*b] = g0; keyb[2*b+1] = g1;
  }
  int ka = blockIdx.x * 256 + threadIdx.x;
  int a = ka % AA, pos = ka / AA, x = pos & 63, y = pos >> 6;
  int pre = 0; bool mine = false;
#pragma unroll
  for (int t = 0; t < 9; ++t) {
    int hw2 = c_awi[t] - 1, hh2 = c_ahi[t] - 1;
    int xlo = (hw2 + 16) >> 5, xhi = (2032 - hw2) >> 5;
    int ylo = (hh2 + 16) >> 5, yhi = (2032 - hh2) >> 5;
    int nx = xhi - xlo + 1;
    int rb = min(y, yhi + 1) - ylo; rb = max(rb, 0);  // rows fully before y
    pre += nx * rb;
    bool iny = (y >= ylo) && (y <= yhi);
    if (iny) {
      int cb = min(x, xhi + 1) - xlo; cb = max(cb, 0); // cols before x in row y
      pre += cb;
      bool ins = (x >= xlo) && (x <= xhi);
      if (ins && t < a) pre++;
      if (t == a) mine = ins;
    }
  }
  inv[ka] = mine ? pre : -1;
  if (mine) inside[pre] = ka;
  if (ka == KAT - 1) *dN = pre + (mine ? 1 : 0);
}

// ---- K2: per-(b,g) max IoU; GCH gts per block amortize anchor decode ----
__global__ void __launch_bounds__(256) k_gtmax(const float* __restrict__ gt,
                                               const int* __restrict__ inside,
                                               const int* __restrict__ dN,
                                               float* __restrict__ gt_max) {
  int b = blockIdx.y;
  int g0 = blockIdx.x * GCH;
  const float4* __restrict__ gb4 = (const float4*)(gt + b * GG * 4);
  float4 G[GCH]; float gar[GCH]; float best[GCH];
#pragma unroll
  for (int c = 0; c < GCH; ++c) {
    G[c] = gb4[g0 + c];
    gar[c] = ((G[c].z - G[c].x) + 1.0f) * ((G[c].w - G[c].y) + 1.0f);
    best[c] = -1.0f;
  }
  int N = min(*dN, NCAP);
  for (int i = threadIdx.x; i < N; i += 256) {
    int ka = inside[i];
    int a, x, y; float ax1, ay1, ax2, ay2;
    anchor_box(ka, a, x, y, ax1, ay1, ax2, ay2);
    float aar = ((ax2 - ax1) + 1.0f) * ((ay2 - ay1) + 1.0f);
#pragma unroll
    for (int c = 0; c < GCH; ++c)
      best[c] = fmaxf(best[c], iou_pre(ax1, ay1, ax2, ay2, aar,
                                       G[c].x, G[c].y, G[c].z, G[c].w, gar[c]));
  }
  __shared__ float red[GCH][4];
  int lane = threadIdx.x & 63, wv = threadIdx.x >> 6;
#pragma unroll
  for (int c = 0; c < GCH; ++c) {
    float v = best[c];
    for (int off = 32; off > 0; off >>= 1) v = fmaxf(v, __shfl_down(v, off));
    if (lane == 0) red[c][wv] = v;
  }
  __syncthreads();
  if (threadIdx.x < GCH) {
    int c = threadIdx.x;
    float v = fmaxf(fmaxf(red[c][0], red[c][1]), fmaxf(red[c][2], red[c][3]));
    gt_max[b * GG + g0 + c] = v;
  }
}

// ---- K3: labels/argmax/candidates — 4 anchors/thread, uniform gt loads --
__global__ void __launch_bounds__(256) k_labels(
    const float* __restrict__ gt, const int* __restrict__ inside,
    const int* __restrict__ dN, const float* __restrict__ gt_max,
    const unsigned* __restrict__ keyf, const unsigned* __restrict__ keyb,
    signed char* __restrict__ lab, unsigned char* __restrict__ am,
    int* __restrict__ fg_cnt, int* __restrict__ fg_idx, float* __restrict__ fg_pri,
    int* __restrict__ bg_cnt, int* __restrict__ bg_idx, float* __restrict__ bg_pri) {
  int b = blockIdx.y;
  int N = min(*dN, NCAP);
  int i0 = blockIdx.x * (256 * ANPT) + threadIdx.x;
  const float4* __restrict__ gb4 = (const float4*)(gt + b * GG * 4);
  const float* __restrict__ gm = gt_max + b * GG;

  int ia[ANPT]; bool act[ANPT];
  float ax1[ANPT], ay1[ANPT], ax2[ANPT], ay2[ANPT], aar[ANPT], best[ANPT];
  int argg[ANPT]; bool hit[ANPT];
#pragma unroll
  for (int c = 0; c < ANPT; ++c) {
    int i = i0 + c * 256; ia[c] = i; act[c] = (i < N);
    int ka = act[c] ? inside[i] : 0;
    int a, x, y;
    anchor_box(ka, a, x, y, ax1[c], ay1[c], ax2[c], ay2[c]);
    aar[c] = ((ax2[c] - ax1[c]) + 1.0f) * ((ay2[c] - ay1[c]) + 1.0f);
    best[c] = -1.0f; argg[c] = 0; hit[c] = false;
  }
  for (int g = 0; g < GG; ++g) {
    float4 gbx = gb4[g];                           // uniform -> s_load
    float gar = ((gbx.z - gbx.x) + 1.0f) * ((gbx.w - gbx.y) + 1.0f);
    float smg = gm[g];
#pragma unroll
    for (int c = 0; c < ANPT; ++c) {
      float ov = iou_pre(ax1[c], ay1[c], ax2[c], ay2[c], aar[c],
                         gbx.x, gbx.y, gbx.z, gbx.w, gar);
      if (ov > best[c]) { best[c] = ov; argg[c] = g; }  // first-max wins
      hit[c] = hit[c] || ((ov == smg) && (smg > 0.0f));
    }
  }
#pragma unroll
  for (int c = 0; c < ANPT; ++c) {
    if (!act[c]) continue;
    int label = (hit[c] || best[c] >= 0.7f) ? 1 : ((best[c] < 0.3f) ? 0 : -1);
    lab[b * NCAP + ia[c]] = (signed char)label;
    am[b * NCAP + ia[c]]  = (unsigned char)argg[c];
    if (label == 1) {
      float p = pri_uniform(keyf[2*b], keyf[2*b+1], ia[c]);
      int cc = atomicAdd(&fg_cnt[b], 1);
      if (cc < MAXC) { fg_idx[b * MAXC + cc] = ia[c]; fg_pri[b * MAXC + cc] = p; }
    } else if (label == 0) {
      float p = pri_uniform(keyb[2*b], keyb[2*b+1], ia[c]);
      if (p < BG_T) {
        int cc = atomicAdd(&bg_cnt[b], 1);
        if (cc < MAXC) { bg_idx[b * MAXC + cc] = ia[c]; bg_pri[b * MAXC + cc] = p; }
      }
    }
  }
}

// Packed (pri,idx) key: pri >= 0 so float bits preserve order as u32;
// low 32 bits = compact index -> u64 '<' == stable-argsort order.
__device__ __forceinline__ unsigned long long pack_key(float p, int i) {
  return ((unsigned long long)__float_as_uint(p) << 32) | (unsigned)i;
}

// ---- K4: merged fg/bg subsample via LDS rank-select ---------------------
__global__ void __launch_bounds__(1024) k_select(
    const int* __restrict__ fg_cnt, const int* __restrict__ fg_idx, const float* __restrict__ fg_pri,
    const int* __restrict__ bg_cnt, const int* __restrict__ bg_idx, const float* __restrict__ bg_pri,
    signed char* __restrict__ lab) {
  __shared__ unsigned long long sk[MAXC];
  int b = blockIdx.x & (BB - 1);
  if (blockIdx.x < BB) {        // fg role: demote rank >= NUMFG
    int F = min(fg_cnt[b], MAXC);
    if (F <= NUMFG) return;
    for (int c = threadIdx.x; c < F; c += blockDim.x)
      sk[c] = pack_key(fg_pri[b * MAXC + c], fg_idx[b * MAXC + c]);
    __syncthreads();
    for (int c = threadIdx.x; c < F; c += blockDim.x) {
      unsigned long long me = sk[c];
      int rank = 0;
      for (int j = 0; j < F; ++j) rank += (sk[j] < me) ? 1 : 0;
      if (rank >= NUMFG) lab[b * NCAP + (int)(me & 0xFFFFFFFFu)] = -1;
    }
  } else {                       // bg role: mark rank < nk as kept (2)
    int nk = RPNB - min(fg_cnt[b], NUMFG);
    int C = min(bg_cnt[b], MAXC);
    for (int c = threadIdx.x; c < C; c += blockDim.x)
      sk[c] = pack_key(bg_pri[b * MAXC + c], bg_idx[b * MAXC + c]);
    __syncthreads();
    for (int c = threadIdx.x; c < C; c += blockDim.x) {
      unsigned long long me = sk[c];
      int rank = 0;
      for (int j = 0; j < C; ++j) rank += (sk[j] < me) ? 1 : 0;
      if (rank < nk) lab[b * NCAP + (int)(me & 0xFFFFFFFFu)] = 2;
    }
  }
}

// ---- K5: merged fill+scatter, output-ordered, fully coalesced -----------
__global__ void k_out(const float* __restrict__ gt, const int* __restrict__ inv,
                      const signed char* __restrict__ lab, const unsigned char* __restrict__ am,
                      float* __restrict__ out) {
  int b = blockIdx.y;
  int t = blockIdx.x * 256 + threadIdx.x;   // t = a*4096 + y*64 + x  (output order)
  int a = t >> 12, pos = t & 4095;
  int ka = pos * AA + a;
  int i = inv[ka];
  float lv = -1.0f, t0 = 0.f, t1 = 0.f, t2 = 0.f, t3 = 0.f;
  if (i >= 0) {
    signed char v = lab[b * NCAP + i];
    lv = (v == 1) ? 1.0f : ((v == 2) ? 0.0f : -1.0f);
    if (v == 1) {
      int y = pos >> 6, x = pos & 63;
      float ax1, ay1, ax2, ay2;
      box_from_ayx(a, x, y, ax1, ay1, ax2, ay2);
      int g = am[b * NCAP + i];
      const float* gr = gt + (b * GG + g) * 4;
      float gx1 = gr[0], gy1 = gr[1], gx2 = gr[2], gy2 = gr[3];
      float aw = (ax2 - ax1) + 1.0f, ah = (ay2 - ay1) + 1.0f;
      float acx = ax1 + 0.5f * (aw - 1.0f), acy = ay1 + 0.5f * (ah - 1.0f);
      float gw = (gx2 - gx1) + 1.0f, gh = (gy2 - gy1) + 1.0f;
      float gcx = gx1 + 0.5f * (gw - 1.0f), gcy = gy1 + 0.5f * (gh - 1.0f);
      t0 = (gcx - acx) / aw;
      t1 = (gcy - acy) / ah;
      t2 = logf(gw / aw);
      t3 = logf(gh / ah);
    }
  }
  out[b * KAT + t] = lv;
  float* rb = out + LAB_SZ + b * (4 * KAT) + (a * 4) * 4096 + pos;
  rb[0] = t0; rb[4096] = t1; rb[2 * 4096] = t2; rb[3 * 4096] = t3;
}

extern "C" void kernel_launch(void* const* d_in, const int* in_sizes, int n_in,
                              void* d_out, int out_size, void* d_ws, size_t ws_size,
                              hipStream_t stream) {
  const float* gt = (const float*)d_in[0];
  float* out = (float*)d_out;

  char* w = (char*)d_ws;
  int* dN          = (int*)w;            w += 256;
  int* fg_cnt      = (int*)w;            w += 256;
  int* bg_cnt      = (int*)w;            w += 256;
  unsigned* keyf   = (unsigned*)w;       w += 256;
  unsigned* keyb   = (unsigned*)w;       w += 256;
  float* gt_max    = (float*)w;          w += BB*GG*sizeof(float);    // 6400
  int* inside      = (int*)w;            w += KAT*sizeof(int);        // 147456
  int* inv         = (int*)w;            w += KAT*sizeof(int);        // 147456
  signed char* lab = (signed char*)w;    w += BB*NCAP;                // 655360
  unsigned char* am= (unsigned char*)w;  w += BB*NCAP;                // 655360
  int* fg_idx      = (int*)w;            w += BB*MAXC*sizeof(int);
  float* fg_pri    = (float*)w;          w += BB*MAXC*sizeof(float);
  int* bg_idx      = (int*)w;            w += BB*MAXC*sizeof(int);
  float* bg_pri    = (float*)w;          w += BB*MAXC*sizeof(float);
  // total ~3.8 MB of d_ws

  k_prep<<<KAT/256, 256, 0, stream>>>(inside, inv, dN, keyf, keyb, fg_cnt, bg_cnt);
  k_gtmax<<<dim3(GG/GCH, BB), 256, 0, stream>>>(gt, inside, dN, gt_max);
  k_labels<<<dim3(NCAP/(256*ANPT), BB), 256, 0, stream>>>(gt, inside, dN, gt_max, keyf, keyb,
                                                          lab, am, fg_cnt, fg_idx, fg_pri,
                                                          bg_cnt, bg_idx, bg_pri);
  k_select<<<2*BB, 1024, 0, stream>>>(fg_cnt, fg_idx, fg_pri, bg_cnt, bg_idx, bg_pri, lab);
  k_out<<<dim3(KAT/256, BB), 256, 0, stream>>>(gt, inv, lab, am, out);
}

// Round 4
// 195.002 us; speedup vs baseline: 3.3999x; 1.1556x over previous
//
#include <hip/hip_runtime.h>

#pragma clang fp contract(off)

// Problem constants (fixed by setup_inputs): B=32, G=50, H=W=64, A=9.
#define BB 32
#define GG 50
#define AA 9
#define HH 64
#define WW 64
#define KAT (HH*WW*AA)          // 36864 total anchors
#define NCAP 20480              // cap on inside-anchor count (actual = 18624)
#define MAXC 4096               // candidate list cap per image
#define NUMFG 128               // int(0.5 * 256)
#define RPNB 256
#define BG_T 0.05f              // bg priority pre-filter (256th smallest ~0.0143)
#define LAB_SZ (BB*AA*HH*WW)    // 1179648
#define REG_SZ (LAB_SZ*4)       // 4718592
#define ANPT 4                  // anchors per thread in k_labels
#define GCH 5                   // gts per block in k_gtmax
#define ACH 4                   // anchor chunks in k_gtmax

// Anchor (w,h) per type, order = ratios{0.5,1,2} x scales{8,16,32}
__constant__ float c_aw[9] = {184.f,368.f,736.f,128.f,256.f,512.f, 88.f,176.f,352.f};
__constant__ float c_ah[9] = { 96.f,192.f,384.f,128.f,256.f,512.f,176.f,352.f,704.f};
__constant__ int   c_awi[9] = {184,368,736,128,256,512, 88,176,352};
__constant__ int   c_ahi[9] = { 96,192,384,128,256,512,176,352,704};

__device__ __forceinline__ unsigned rotl32(unsigned v, int d) {
  return (v << d) | (v >> (32 - d));
}

// Threefry-2x32, 20 rounds — matches jax._src.prng.threefry2x32
__device__ __forceinline__ void tf2x32(unsigned k0, unsigned k1,
                                       unsigned x0, unsigned x1,
                                       unsigned &o0, unsigned &o1) {
  unsigned ks2 = k0 ^ k1 ^ 0x1BD11BDAu;
  x0 += k0; x1 += k1;
#define TF_R(r) { x0 += x1; x1 = rotl32(x1, (r)); x1 ^= x0; }
  TF_R(13) TF_R(15) TF_R(26) TF_R(6)
  x0 += k1;  x1 += ks2 + 1u;
  TF_R(17) TF_R(29) TF_R(16) TF_R(24)
  x0 += ks2; x1 += k0 + 2u;
  TF_R(13) TF_R(15) TF_R(26) TF_R(6)
  x0 += k0;  x1 += k1 + 3u;
  TF_R(17) TF_R(29) TF_R(16) TF_R(24)
  x0 += k1;  x1 += ks2 + 4u;
  TF_R(13) TF_R(15) TF_R(26) TF_R(6)
  x0 += ks2; x1 += k0 + 5u;
#undef TF_R
  o0 = x0; o1 = x1;
}

__device__ __forceinline__ float bits_to_uniform(unsigned bits) {
  return __uint_as_float((bits >> 9) | 0x3f800000u) - 1.0f;
}

// uniform(key,(N,)) word i — jax_threefry_partitionable=True path (verified R1)
__device__ __forceinline__ float pri_uniform(unsigned k0, unsigned k1, int i) {
  unsigned o0, o1;
  tf2x32(k0, k1, 0u, (unsigned)i, o0, o1);
  return bits_to_uniform(o0 ^ o1);
}

__device__ __forceinline__ void box_from_ayx(int a, int x, int y,
                                             float &ax1, float &ay1, float &ax2, float &ay2) {
  float hw = 0.5f * (c_aw[a] - 1.0f);
  float hh = 0.5f * (c_ah[a] - 1.0f);
  float cx = (float)(16 * x) + 7.5f;
  float cy = (float)(16 * y) + 7.5f;
  ax1 = cx - hw; ay1 = cy - hh; ax2 = cx + hw; ay2 = cy + hh;
}

// IoU core with precomputed areas; op order exactly as reference (contract off).
__device__ __forceinline__ float iou_pre(float ax1, float ay1, float ax2, float ay2, float area_a,
                                         float gx1, float gy1, float gx2, float gy2, float area_g) {
  float iw = (fminf(ax2, gx2) - fmaxf(ax1, gx1)) + 1.0f; iw = fmaxf(iw, 0.0f);
  float ih = (fminf(ay2, gy2) - fmaxf(ay1, gy1)) + 1.0f; ih = fmaxf(ih, 0.0f);
  float inter = iw * ih;
  return inter / ((area_a + area_g) - inter);
}

// ---- K1: analytic compact (no scan) + box table + init ------------------
// Anchor-box float math is exact (multiples of 0.5 < 2048), so the inside
// test reduces to integer ranges; each thread computes its global prefix
// analytically. Also emits abox/aar tables so later kernels skip decode.
__global__ void k_prep(int* __restrict__ inside, int* __restrict__ inv, int* __restrict__ dN,
                       float4* __restrict__ abox, float* __restrict__ aar,
                       unsigned* __restrict__ keyf, unsigned* __restrict__ keyb,
                       int* __restrict__ fg_cnt, int* __restrict__ bg_cnt,
                       unsigned* __restrict__ gt_max_u) {
  int tid = blockIdx.x * 256 + threadIdx.x;
  if (tid < BB) {
    int b = tid;
    fg_cnt[b] = 0; bg_cnt[b] = 0;
    unsigned h, l, f0, f1, g0, g1;
    tf2x32(0u, 42u, 0u, (unsigned)b, h, l);      // split(key(42),32)[b]
    tf2x32(h, l, 0u, 0u, f0, f1);                // kf
    tf2x32(h, l, 0u, 1u, g0, g1);                // kb
    keyf[2*b] = f0; keyf[2*b+1] = f1;
    keyb[2*b] = g0; keyb[2*b+1] = g1;
  }
  if (tid < BB * GG) gt_max_u[tid] = 0u;         // float 0.0 bits
  int ka = tid;
  int a = ka % AA, pos = ka / AA, x = pos & 63, y = pos >> 6;
  int pre = 0; bool mine = false;
#pragma unroll
  for (int t = 0; t < 9; ++t) {
    int hw2 = c_awi[t] - 1, hh2 = c_ahi[t] - 1;
    int xlo = (hw2 + 16) >> 5, xhi = (2032 - hw2) >> 5;
    int ylo = (hh2 + 16) >> 5, yhi = (2032 - hh2) >> 5;
    int nx = xhi - xlo + 1;
    int rb = min(y, yhi + 1) - ylo; rb = max(rb, 0);  // rows fully before y
    pre += nx * rb;
    bool iny = (y >= ylo) && (y <= yhi);
    if (iny) {
      int cb = min(x, xhi + 1) - xlo; cb = max(cb, 0); // cols before x in row y
      pre += cb;
      bool ins = (x >= xlo) && (x <= xhi);
      if (ins && t < a) pre++;
      if (t == a) mine = ins;
    }
  }
  inv[ka] = mine ? pre : -1;
  if (mine) {
    inside[pre] = ka;
    float ax1, ay1, ax2, ay2;
    box_from_ayx(a, x, y, ax1, ay1, ax2, ay2);
    abox[pre] = make_float4(ax1, ay1, ax2, ay2);
    aar[pre] = ((ax2 - ax1) + 1.0f) * ((ay2 - ay1) + 1.0f);
  }
  if (ka == KAT - 1) *dN = pre + (mine ? 1 : 0);
}

// ---- K2: per-(b,g) max IoU; gt-chunk x anchor-chunk grid, atomicMax -----
__global__ void __launch_bounds__(256) k_gtmax(const float* __restrict__ gt,
                                               const float4* __restrict__ abox,
                                               const float* __restrict__ aar,
                                               const int* __restrict__ dN,
                                               unsigned* __restrict__ gt_max_u) {
  int b = blockIdx.z;
  int g0 = blockIdx.x * GCH;
  int ac = blockIdx.y;
  const float4* __restrict__ gb4 = (const float4*)(gt + b * GG * 4);
  float4 G[GCH]; float gar[GCH]; float best[GCH];
#pragma unroll
  for (int c = 0; c < GCH; ++c) {
    G[c] = gb4[g0 + c];                           // uniform -> s_load
    gar[c] = ((G[c].z - G[c].x) + 1.0f) * ((G[c].w - G[c].y) + 1.0f);
    best[c] = 0.0f;                               // IoU >= 0 always
  }
  int N = min(*dN, NCAP);
  int chunk = (N + ACH - 1) / ACH;
  int i1 = min((ac + 1) * chunk, N);
  for (int i = ac * chunk + threadIdx.x; i < i1; i += 256) {
    float4 A = abox[i];
    float av = aar[i];
#pragma unroll
    for (int c = 0; c < GCH; ++c)
      best[c] = fmaxf(best[c], iou_pre(A.x, A.y, A.z, A.w, av,
                                       G[c].x, G[c].y, G[c].z, G[c].w, gar[c]));
  }
  __shared__ float red[GCH][4];
  int lane = threadIdx.x & 63, wv = threadIdx.x >> 6;
#pragma unroll
  for (int c = 0; c < GCH; ++c) {
    float v = best[c];
    for (int off = 32; off > 0; off >>= 1) v = fmaxf(v, __shfl_down(v, off));
    if (lane == 0) red[c][wv] = v;
  }
  __syncthreads();
  if (threadIdx.x < GCH) {
    int c = threadIdx.x;
    float v = fmaxf(fmaxf(red[c][0], red[c][1]), fmaxf(red[c][2], red[c][3]));
    atomicMax(&gt_max_u[b * GG + g0 + c], __float_as_uint(v));  // v >= 0
  }
}

// ---- K3: labels/argmax/candidates — LDS gt staging, 4 anchors/thread ----
__global__ void __launch_bounds__(256, 4) k_labels(
    const float* __restrict__ gt, const float4* __restrict__ abox,
    const float* __restrict__ aar,
    const int* __restrict__ dN, const float* __restrict__ gt_max,
    const unsigned* __restrict__ keyf, const unsigned* __restrict__ keyb,
    signed char* __restrict__ lab, unsigned char* __restrict__ am,
    int* __restrict__ fg_cnt, int* __restrict__ fg_idx, float* __restrict__ fg_pri,
    int* __restrict__ bg_cnt, int* __restrict__ bg_idx, float* __restrict__ bg_pri) {
  __shared__ float4 sbox[GG];
  __shared__ float2 sga[GG];      // (area_g, gt_max' = m>0 ? m : -1)
  int b = blockIdx.y;
  if (threadIdx.x < GG) {
    float4 gbx = ((const float4*)(gt + b * GG * 4))[threadIdx.x];
    sbox[threadIdx.x] = gbx;
    float gar = ((gbx.z - gbx.x) + 1.0f) * ((gbx.w - gbx.y) + 1.0f);
    float m = gt_max[b * GG + threadIdx.x];
    sga[threadIdx.x] = make_float2(gar, (m > 0.0f) ? m : -1.0f);
  }
  __syncthreads();
  int N = min(*dN, NCAP);
  int i0 = blockIdx.x * (256 * ANPT) + threadIdx.x;

  float4 A[ANPT]; float av[ANPT], best[ANPT];
  int argg[ANPT]; bool hit[ANPT];
#pragma unroll
  for (int c = 0; c < ANPT; ++c) {
    int i = i0 + c * 256;                     // i < NCAP by grid construction
    A[c] = abox[i];
    av[c] = aar[i];
    best[c] = -1.0f; argg[c] = 0; hit[c] = false;
  }
#pragma unroll 2
  for (int g = 0; g < GG; ++g) {
    float4 gbx = sbox[g];
    float2 ga = sga[g];
#pragma unroll
    for (int c = 0; c < ANPT; ++c) {
      float ov = iou_pre(A[c].x, A[c].y, A[c].z, A[c].w, av[c],
                         gbx.x, gbx.y, gbx.z, gbx.w, ga.x);
      if (ov > best[c]) { best[c] = ov; argg[c] = g; }  // first-max wins
      hit[c] = hit[c] || (ov == ga.y);                  // ga.y=-1 if gt_max<=0
    }
  }
#pragma unroll
  for (int c = 0; c < ANPT; ++c) {
    int i = i0 + c * 256;
    if (i >= N) continue;
    int label = (hit[c] || best[c] >= 0.7f) ? 1 : ((best[c] < 0.3f) ? 0 : -1);
    lab[b * NCAP + i] = (signed char)label;
    am[b * NCAP + i]  = (unsigned char)argg[c];
    if (label == 1) {
      float p = pri_uniform(keyf[2*b], keyf[2*b+1], i);
      int cc = atomicAdd(&fg_cnt[b], 1);
      if (cc < MAXC) { fg_idx[b * MAXC + cc] = i; fg_pri[b * MAXC + cc] = p; }
    } else if (label == 0) {
      float p = pri_uniform(keyb[2*b], keyb[2*b+1], i);
      if (p < BG_T) {
        int cc = atomicAdd(&bg_cnt[b], 1);
        if (cc < MAXC) { bg_idx[b * MAXC + cc] = i; bg_pri[b * MAXC + cc] = p; }
      }
    }
  }
}

// Packed (pri,idx) key: pri >= 0 so float bits preserve order as u32;
// low 32 bits = compact index -> u64 '<' == stable-argsort order.
__device__ __forceinline__ unsigned long long pack_key(float p, int i) {
  return ((unsigned long long)__float_as_uint(p) << 32) | (unsigned)i;
}

// ---- K4: merged fg/bg subsample via LDS rank-select ---------------------
__global__ void __launch_bounds__(1024) k_select(
    const int* __restrict__ fg_cnt, const int* __restrict__ fg_idx, const float* __restrict__ fg_pri,
    const int* __restrict__ bg_cnt, const int* __restrict__ bg_idx, const float* __restrict__ bg_pri,
    signed char* __restrict__ lab) {
  __shared__ unsigned long long sk[MAXC];
  int b = blockIdx.x & (BB - 1);
  if (blockIdx.x < BB) {        // fg role: demote rank >= NUMFG
    int F = min(fg_cnt[b], MAXC);
    if (F <= NUMFG) return;
    for (int c = threadIdx.x; c < F; c += blockDim.x)
      sk[c] = pack_key(fg_pri[b * MAXC + c], fg_idx[b * MAXC + c]);
    __syncthreads();
    for (int c = threadIdx.x; c < F; c += blockDim.x) {
      unsigned long long me = sk[c];
      int rank = 0;
      for (int j = 0; j < F; ++j) rank += (sk[j] < me) ? 1 : 0;
      if (rank >= NUMFG) lab[b * NCAP + (int)(me & 0xFFFFFFFFu)] = -1;
    }
  } else {                       // bg role: mark rank < nk as kept (2)
    int nk = RPNB - min(fg_cnt[b], NUMFG);
    int C = min(bg_cnt[b], MAXC);
    for (int c = threadIdx.x; c < C; c += blockDim.x)
      sk[c] = pack_key(bg_pri[b * MAXC + c], bg_idx[b * MAXC + c]);
    __syncthreads();
    for (int c = threadIdx.x; c < C; c += blockDim.x) {
      unsigned long long me = sk[c];
      int rank = 0;
      for (int j = 0; j < C; ++j) rank += (sk[j] < me) ? 1 : 0;
      if (rank < nk) lab[b * NCAP + (int)(me & 0xFFFFFFFFu)] = 2;
    }
  }
}

// ---- K5: merged fill+scatter, output-ordered, fully coalesced -----------
__global__ void k_out(const float* __restrict__ gt, const int* __restrict__ inv,
                      const signed char* __restrict__ lab, const unsigned char* __restrict__ am,
                      float* __restrict__ out) {
  int b = blockIdx.y;
  int t = blockIdx.x * 256 + threadIdx.x;   // t = a*4096 + y*64 + x  (output order)
  int a = t >> 12, pos = t & 4095;
  int ka = pos * AA + a;
  int i = inv[ka];
  float lv = -1.0f, t0 = 0.f, t1 = 0.f, t2 = 0.f, t3 = 0.f;
  if (i >= 0) {
    signed char v = lab[b * NCAP + i];
    lv = (v == 1) ? 1.0f : ((v == 2) ? 0.0f : -1.0f);
    if (v == 1) {
      int y = pos >> 6, x = pos & 63;
      float ax1, ay1, ax2, ay2;
      box_from_ayx(a, x, y, ax1, ay1, ax2, ay2);
      int g = am[b * NCAP + i];
      const float* gr = gt + (b * GG + g) * 4;
      float gx1 = gr[0], gy1 = gr[1], gx2 = gr[2], gy2 = gr[3];
      float aw = (ax2 - ax1) + 1.0f, ah = (ay2 - ay1) + 1.0f;
      float acx = ax1 + 0.5f * (aw - 1.0f), acy = ay1 + 0.5f * (ah - 1.0f);
      float gw = (gx2 - gx1) + 1.0f, gh = (gy2 - gy1) + 1.0f;
      float gcx = gx1 + 0.5f * (gw - 1.0f), gcy = gy1 + 0.5f * (gh - 1.0f);
      t0 = (gcx - acx) / aw;
      t1 = (gcy - acy) / ah;
      t2 = logf(gw / aw);
      t3 = logf(gh / ah);
    }
  }
  out[b * KAT + t] = lv;
  float* rb = out + LAB_SZ + b * (4 * KAT) + (a * 4) * 4096 + pos;
  rb[0] = t0; rb[4096] = t1; rb[2 * 4096] = t2; rb[3 * 4096] = t3;
}

extern "C" void kernel_launch(void* const* d_in, const int* in_sizes, int n_in,
                              void* d_out, int out_size, void* d_ws, size_t ws_size,
                              hipStream_t stream) {
  const float* gt = (const float*)d_in[0];
  float* out = (float*)d_out;

  char* w = (char*)d_ws;
  int* dN          = (int*)w;            w += 256;
  int* fg_cnt      = (int*)w;            w += 256;
  int* bg_cnt      = (int*)w;            w += 256;
  unsigned* keyf   = (unsigned*)w;       w += 256;
  unsigned* keyb   = (unsigned*)w;       w += 256;
  float* gt_max    = (float*)w;          w += ((BB*GG*4 + 255)/256)*256;  // 6400 -> 6656
  int* inside      = (int*)w;            w += KAT*sizeof(int);        // 147456
  int* inv         = (int*)w;            w += KAT*sizeof(int);        // 147456
  float4* abox     = (float4*)w;         w += NCAP*sizeof(float4);    // 327680 (16B aligned)
  float* aar       = (float*)w;          w += NCAP*sizeof(float);     // 81920
  signed char* lab = (signed char*)w;    w += BB*NCAP;                // 655360
  unsigned char* am= (unsigned char*)w;  w += BB*NCAP;                // 655360
  int* fg_idx      = (int*)w;            w += BB*MAXC*sizeof(int);
  float* fg_pri    = (float*)w;          w += BB*MAXC*sizeof(float);
  int* bg_idx      = (int*)w;            w += BB*MAXC*sizeof(int);
  float* bg_pri    = (float*)w;          w += BB*MAXC*sizeof(float);
  // total ~4.2 MB of d_ws

  k_prep<<<KAT/256, 256, 0, stream>>>(inside, inv, dN, abox, aar, keyf, keyb,
                                      fg_cnt, bg_cnt, (unsigned*)gt_max);
  k_gtmax<<<dim3(GG/GCH, ACH, BB), 256, 0, stream>>>(gt, abox, aar, dN, (unsigned*)gt_max);
  k_labels<<<dim3(NCAP/(256*ANPT), BB), 256, 0, stream>>>(gt, abox, aar, dN, gt_max,
                                                          keyf, keyb, lab, am,
                                                          fg_cnt, fg_idx, fg_pri,
                                                          bg_cnt, bg_idx, bg_pri);
  k_select<<<2*BB, 1024, 0, stream>>>(fg_cnt, fg_idx, fg_pri, bg_cnt, bg_idx, bg_pri, lab);
  k_out<<<dim3(KAT/256, BB), 256, 0, stream>>>(gt, inv, lab, am, out);
}

// Round 5
// 187.825 us; speedup vs baseline: 3.5298x; 1.0382x over previous
//
#include <hip/hip_runtime.h>

#pragma clang fp contract(off)

// Problem constants (fixed by setup_inputs): B=32, G=50, H=W=64, A=9.
#define BB 32
#define GG 50
#define AA 9
#define HH 64
#define WW 64
#define KAT (HH*WW*AA)          // 36864 total anchors
#define NCAP 20480              // cap on inside-anchor count (actual = 18624)
#define MAXC 4096               // candidate list cap per image
#define NUMFG 128               // int(0.5 * 256)
#define RPNB 256
#define BG_T 0.05f              // bg priority pre-filter (256th smallest ~0.0143)
#define LAB_SZ (BB*AA*HH*WW)    // 1179648
#define REG_SZ (LAB_SZ*4)       // 4718592
#define ANPT 2                  // anchors per thread in k_labels (grid-occupancy: 1280 blocks)
#define GCH 5                   // gts per block in k_gtmax
#define ACH 8                   // anchor chunks in k_gtmax

// Anchor (w,h) per type, order = ratios{0.5,1,2} x scales{8,16,32}
__constant__ float c_aw[9] = {184.f,368.f,736.f,128.f,256.f,512.f, 88.f,176.f,352.f};
__constant__ float c_ah[9] = { 96.f,192.f,384.f,128.f,256.f,512.f,176.f,352.f,704.f};
__constant__ int   c_awi[9] = {184,368,736,128,256,512, 88,176,352};
__constant__ int   c_ahi[9] = { 96,192,384,128,256,512,176,352,704};

__device__ __forceinline__ unsigned rotl32(unsigned v, int d) {
  return (v << d) | (v >> (32 - d));
}

// Threefry-2x32, 20 rounds — matches jax._src.prng.threefry2x32
__device__ __forceinline__ void tf2x32(unsigned k0, unsigned k1,
                                       unsigned x0, unsigned x1,
                                       unsigned &o0, unsigned &o1) {
  unsigned ks2 = k0 ^ k1 ^ 0x1BD11BDAu;
  x0 += k0; x1 += k1;
#define TF_R(r) { x0 += x1; x1 = rotl32(x1, (r)); x1 ^= x0; }
  TF_R(13) TF_R(15) TF_R(26) TF_R(6)
  x0 += k1;  x1 += ks2 + 1u;
  TF_R(17) TF_R(29) TF_R(16) TF_R(24)
  x0 += ks2; x1 += k0 + 2u;
  TF_R(13) TF_R(15) TF_R(26) TF_R(6)
  x0 += k0;  x1 += k1 + 3u;
  TF_R(17) TF_R(29) TF_R(16) TF_R(24)
  x0 += k1;  x1 += ks2 + 4u;
  TF_R(13) TF_R(15) TF_R(26) TF_R(6)
  x0 += ks2; x1 += k0 + 5u;
#undef TF_R
  o0 = x0; o1 = x1;
}

__device__ __forceinline__ float bits_to_uniform(unsigned bits) {
  return __uint_as_float((bits >> 9) | 0x3f800000u) - 1.0f;
}

// uniform(key,(N,)) word i — jax_threefry_partitionable=True path (verified R1)
__device__ __forceinline__ float pri_uniform(unsigned k0, unsigned k1, int i) {
  unsigned o0, o1;
  tf2x32(k0, k1, 0u, (unsigned)i, o0, o1);
  return bits_to_uniform(o0 ^ o1);
}

__device__ __forceinline__ void box_from_ayx(int a, int x, int y,
                                             float &ax1, float &ay1, float &ax2, float &ay2) {
  float hw = 0.5f * (c_aw[a] - 1.0f);
  float hh = 0.5f * (c_ah[a] - 1.0f);
  float cx = (float)(16 * x) + 7.5f;
  float cy = (float)(16 * y) + 7.5f;
  ax1 = cx - hw; ay1 = cy - hh; ax2 = cx + hw; ay2 = cy + hh;
}

// ---- K1: analytic compact (no scan) + box table + init ------------------
// Anchor-box float math is exact (multiples of 0.5 < 2048), so the inside
// test reduces to integer ranges; each thread computes its global prefix
// analytically. Also emits abox/aar tables so later kernels skip decode.
__global__ void k_prep(int* __restrict__ inside, int* __restrict__ inv, int* __restrict__ dN,
                       float4* __restrict__ abox, float* __restrict__ aar,
                       unsigned* __restrict__ keyf, unsigned* __restrict__ keyb,
                       int* __restrict__ fg_cnt, int* __restrict__ bg_cnt,
                       unsigned* __restrict__ gt_max_u) {
  int tid = blockIdx.x * 256 + threadIdx.x;
  if (tid < BB) {
    int b = tid;
    fg_cnt[b] = 0; bg_cnt[b] = 0;
    unsigned h, l, f0, f1, g0, g1;
    tf2x32(0u, 42u, 0u, (unsigned)b, h, l);      // split(key(42),32)[b]
    tf2x32(h, l, 0u, 0u, f0, f1);                // kf
    tf2x32(h, l, 0u, 1u, g0, g1);                // kb
    keyf[2*b] = f0; keyf[2*b+1] = f1;
    keyb[2*b] = g0; keyb[2*b+1] = g1;
  }
  if (tid < BB * GG) gt_max_u[tid] = 0u;         // float 0.0 bits
  int ka = tid;
  int a = ka % AA, pos = ka / AA, x = pos & 63, y = pos >> 6;
  int pre = 0; bool mine = false;
#pragma unroll
  for (int t = 0; t < 9; ++t) {
    int hw2 = c_awi[t] - 1, hh2 = c_ahi[t] - 1;
    int xlo = (hw2 + 16) >> 5, xhi = (2032 - hw2) >> 5;
    int ylo = (hh2 + 16) >> 5, yhi = (2032 - hh2) >> 5;
    int nx = xhi - xlo + 1;
    int rb = min(y, yhi + 1) - ylo; rb = max(rb, 0);  // rows fully before y
    pre += nx * rb;
    bool iny = (y >= ylo) && (y <= yhi);
    if (iny) {
      int cb = min(x, xhi + 1) - xlo; cb = max(cb, 0); // cols before x in row y
      pre += cb;
      bool ins = (x >= xlo) && (x <= xhi);
      if (ins && t < a) pre++;
      if (t == a) mine = ins;
    }
  }
  inv[ka] = mine ? pre : -1;
  if (mine) {
    inside[pre] = ka;
    float ax1, ay1, ax2, ay2;
    box_from_ayx(a, x, y, ax1, ay1, ax2, ay2);
    abox[pre] = make_float4(ax1, ay1, ax2, ay2);
    aar[pre] = ((ax2 - ax1) + 1.0f) * ((ay2 - ay1) + 1.0f);
  }
  if (ka == KAT - 1) *dN = pre + (mine ? 1 : 0);
}

// ---- K2: per-(b,g) max IoU; gt-chunk x anchor-chunk grid, atomicMax -----
__global__ void __launch_bounds__(256) k_gtmax(const float* __restrict__ gt,
                                               const float4* __restrict__ abox,
                                               const float* __restrict__ aar,
                                               const int* __restrict__ dN,
                                               unsigned* __restrict__ gt_max_u) {
  int b = blockIdx.z;
  int g0 = blockIdx.x * GCH;
  int ac = blockIdx.y;
  const float4* __restrict__ gb4 = (const float4*)(gt + b * GG * 4);
  float4 G[GCH]; float gar[GCH]; float best[GCH];
#pragma unroll
  for (int c = 0; c < GCH; ++c) {
    G[c] = gb4[g0 + c];                           // uniform -> s_load
    gar[c] = ((G[c].z - G[c].x) + 1.0f) * ((G[c].w - G[c].y) + 1.0f);
    best[c] = 0.0f;                               // IoU >= 0 always
  }
  int N = min(*dN, NCAP);
  int chunk = (N + ACH - 1) / ACH;
  int i1 = min((ac + 1) * chunk, N);
  for (int i = ac * chunk + threadIdx.x; i < i1; i += 256) {
    float4 A = abox[i];
    float av = aar[i];
#pragma unroll
    for (int c = 0; c < GCH; ++c) {
      float iw = (fminf(A.z, G[c].z) - fmaxf(A.x, G[c].x)) + 1.0f; iw = fmaxf(iw, 0.0f);
      float ih = (fminf(A.w, G[c].w) - fmaxf(A.y, G[c].y)) + 1.0f; ih = fmaxf(ih, 0.0f);
      float inter = iw * ih;
      if (inter > 0.0f)                           // ov==0 can't raise best>=0
        best[c] = fmaxf(best[c], inter / ((av + gar[c]) - inter));
    }
  }
  __shared__ float red[GCH][4];
  int lane = threadIdx.x & 63, wv = threadIdx.x >> 6;
#pragma unroll
  for (int c = 0; c < GCH; ++c) {
    float v = best[c];
    for (int off = 32; off > 0; off >>= 1) v = fmaxf(v, __shfl_down(v, off));
    if (lane == 0) red[c][wv] = v;
  }
  __syncthreads();
  if (threadIdx.x < GCH) {
    int c = threadIdx.x;
    float v = fmaxf(fmaxf(red[c][0], red[c][1]), fmaxf(red[c][2], red[c][3]));
    atomicMax(&gt_max_u[b * GG + g0 + c], __float_as_uint(v));  // v >= 0
  }
}

// ---- K3: labels/argmax/candidates — LDS gt staging, 2 anchors/thread ----
__global__ void __launch_bounds__(256, 4) k_labels(
    const float* __restrict__ gt, const float4* __restrict__ abox,
    const float* __restrict__ aar,
    const int* __restrict__ dN, const float* __restrict__ gt_max,
    const unsigned* __restrict__ keyf, const unsigned* __restrict__ keyb,
    signed char* __restrict__ lab, unsigned char* __restrict__ am,
    int* __restrict__ fg_cnt, int* __restrict__ fg_idx, float* __restrict__ fg_pri,
    int* __restrict__ bg_cnt, int* __restrict__ bg_idx, float* __restrict__ bg_pri) {
  __shared__ float4 sbox[GG];
  __shared__ float2 sga[GG];      // (area_g, gt_max' = m>0 ? m : -1)
  int b = blockIdx.y;
  if (threadIdx.x < GG) {
    float4 gbx = ((const float4*)(gt + b * GG * 4))[threadIdx.x];
    sbox[threadIdx.x] = gbx;
    float gar = ((gbx.z - gbx.x) + 1.0f) * ((gbx.w - gbx.y) + 1.0f);
    float m = gt_max[b * GG + threadIdx.x];
    sga[threadIdx.x] = make_float2(gar, (m > 0.0f) ? m : -1.0f);
  }
  __syncthreads();
  int N = min(*dN, NCAP);
  int i0 = blockIdx.x * (256 * ANPT) + threadIdx.x;

  float4 A[ANPT]; float av[ANPT], best[ANPT];
  int argg[ANPT]; bool hit[ANPT];
#pragma unroll
  for (int c = 0; c < ANPT; ++c) {
    int i = i0 + c * 256;                     // i < NCAP by grid construction
    A[c] = abox[i];
    av[c] = aar[i];
    best[c] = 0.0f; argg[c] = 0; hit[c] = false;   // IoU>=0; strict '>' keeps first-max
  }
#pragma unroll 2
  for (int g = 0; g < GG; ++g) {
    float4 gbx = sbox[g];
    float2 ga = sga[g];
#pragma unroll
    for (int c = 0; c < ANPT; ++c) {
      float iw = (fminf(A[c].z, gbx.z) - fmaxf(A[c].x, gbx.x)) + 1.0f; iw = fmaxf(iw, 0.0f);
      float ih = (fminf(A[c].w, gbx.w) - fmaxf(A[c].y, gbx.y)) + 1.0f; ih = fmaxf(ih, 0.0f);
      float inter = iw * ih;
      if (inter > 0.0f) {       // ov==0: can't beat best>=0, can't equal ga.y (!=0)
        float ov = inter / ((av[c] + ga.x) - inter);
        if (ov > best[c]) { best[c] = ov; argg[c] = g; }  // first-max wins
        hit[c] = hit[c] || (ov == ga.y);                  // ga.y=-1 if gt_max<=0
      }
    }
  }
#pragma unroll
  for (int c = 0; c < ANPT; ++c) {
    int i = i0 + c * 256;
    if (i >= N) continue;
    int label = (hit[c] || best[c] >= 0.7f) ? 1 : ((best[c] < 0.3f) ? 0 : -1);
    lab[b * NCAP + i] = (signed char)label;
    am[b * NCAP + i]  = (unsigned char)argg[c];
    if (label == 1) {
      float p = pri_uniform(keyf[2*b], keyf[2*b+1], i);
      int cc = atomicAdd(&fg_cnt[b], 1);
      if (cc < MAXC) { fg_idx[b * MAXC + cc] = i; fg_pri[b * MAXC + cc] = p; }
    } else if (label == 0) {
      float p = pri_uniform(keyb[2*b], keyb[2*b+1], i);
      if (p < BG_T) {
        int cc = atomicAdd(&bg_cnt[b], 1);
        if (cc < MAXC) { bg_idx[b * MAXC + cc] = i; bg_pri[b * MAXC + cc] = p; }
      }
    }
  }
}

// Packed (pri,idx) key: pri >= 0 so float bits preserve order as u32;
// low 32 bits = compact index -> u64 '<' == stable-argsort order.
__device__ __forceinline__ unsigned long long pack_key(float p, int i) {
  return ((unsigned long long)__float_as_uint(p) << 32) | (unsigned)i;
}

// ---- K4: merged fg/bg subsample via LDS rank-select ---------------------
__global__ void __launch_bounds__(1024) k_select(
    const int* __restrict__ fg_cnt, const int* __restrict__ fg_idx, const float* __restrict__ fg_pri,
    const int* __restrict__ bg_cnt, const int* __restrict__ bg_idx, const float* __restrict__ bg_pri,
    signed char* __restrict__ lab) {
  __shared__ unsigned long long sk[MAXC];
  int b = blockIdx.x & (BB - 1);
  if (blockIdx.x < BB) {        // fg role: demote rank >= NUMFG
    int F = min(fg_cnt[b], MAXC);
    if (F <= NUMFG) return;
    for (int c = threadIdx.x; c < F; c += blockDim.x)
      sk[c] = pack_key(fg_pri[b * MAXC + c], fg_idx[b * MAXC + c]);
    __syncthreads();
    for (int c = threadIdx.x; c < F; c += blockDim.x) {
      unsigned long long me = sk[c];
      int rank = 0;
      for (int j = 0; j < F; ++j) rank += (sk[j] < me) ? 1 : 0;
      if (rank >= NUMFG) lab[b * NCAP + (int)(me & 0xFFFFFFFFu)] = -1;
    }
  } else {                       // bg role: mark rank < nk as kept (2)
    int nk = RPNB - min(fg_cnt[b], NUMFG);
    int C = min(bg_cnt[b], MAXC);
    for (int c = threadIdx.x; c < C; c += blockDim.x)
      sk[c] = pack_key(bg_pri[b * MAXC + c], bg_idx[b * MAXC + c]);
    __syncthreads();
    for (int c = threadIdx.x; c < C; c += blockDim.x) {
      unsigned long long me = sk[c];
      int rank = 0;
      for (int j = 0; j < C; ++j) rank += (sk[j] < me) ? 1 : 0;
      if (rank < nk) lab[b * NCAP + (int)(me & 0xFFFFFFFFu)] = 2;
    }
  }
}

// ---- K5: merged fill+scatter, output-ordered, fully coalesced -----------
__global__ void k_out(const float* __restrict__ gt, const int* __restrict__ inv,
                      const signed char* __restrict__ lab, const unsigned char* __restrict__ am,
                      float* __restrict__ out) {
  int b = blockIdx.y;
  int t = blockIdx.x * 256 + threadIdx.x;   // t = a*4096 + y*64 + x  (output order)
  int a = t >> 12, pos = t & 4095;
  int ka = pos * AA + a;
  int i = inv[ka];
  float lv = -1.0f, t0 = 0.f, t1 = 0.f, t2 = 0.f, t3 = 0.f;
  if (i >= 0) {
    signed char v = lab[b * NCAP + i];
    lv = (v == 1) ? 1.0f : ((v == 2) ? 0.0f : -1.0f);
    if (v == 1) {
      int y = pos >> 6, x = pos & 63;
      float ax1, ay1, ax2, ay2;
      box_from_ayx(a, x, y, ax1, ay1, ax2, ay2);
      int g = am[b * NCAP + i];
      const float* gr = gt + (b * GG + g) * 4;
      float gx1 = gr[0], gy1 = gr[1], gx2 = gr[2], gy2 = gr[3];
      float aw = (ax2 - ax1) + 1.0f, ah = (ay2 - ay1) + 1.0f;
      float acx = ax1 + 0.5f * (aw - 1.0f), acy = ay1 + 0.5f * (ah - 1.0f);
      float gw = (gx2 - gx1) + 1.0f, gh = (gy2 - gy1) + 1.0f;
      float gcx = gx1 + 0.5f * (gw - 1.0f), gcy = gy1 + 0.5f * (gh - 1.0f);
      t0 = (gcx - acx) / aw;
      t1 = (gcy - acy) / ah;
      t2 = logf(gw / aw);
      t3 = logf(gh / ah);
    }
  }
  out[b * KAT + t] = lv;
  float* rb = out + LAB_SZ + b * (4 * KAT) + (a * 4) * 4096 + pos;
  rb[0] = t0; rb[4096] = t1; rb[2 * 4096] = t2; rb[3 * 4096] = t3;
}

extern "C" void kernel_launch(void* const* d_in, const int* in_sizes, int n_in,
                              void* d_out, int out_size, void* d_ws, size_t ws_size,
                              hipStream_t stream) {
  const float* gt = (const float*)d_in[0];
  float* out = (float*)d_out;

  char* w = (char*)d_ws;
  int* dN          = (int*)w;            w += 256;
  int* fg_cnt      = (int*)w;            w += 256;
  int* bg_cnt      = (int*)w;            w += 256;
  unsigned* keyf   = (unsigned*)w;       w += 256;
  unsigned* keyb   = (unsigned*)w;       w += 256;
  float* gt_max    = (float*)w;          w += ((BB*GG*4 + 255)/256)*256;  // 6400 -> 6656
  int* inside      = (int*)w;            w += KAT*sizeof(int);        // 147456
  int* inv         = (int*)w;            w += KAT*sizeof(int);        // 147456
  float4* abox     = (float4*)w;         w += NCAP*sizeof(float4);    // 327680 (16B aligned)
  float* aar       = (float*)w;          w += NCAP*sizeof(float);     // 81920
  signed char* lab = (signed char*)w;    w += BB*NCAP;                // 655360
  unsigned char* am= (unsigned char*)w;  w += BB*NCAP;                // 655360
  int* fg_idx      = (int*)w;            w += BB*MAXC*sizeof(int);
  float* fg_pri    = (float*)w;          w += BB*MAXC*sizeof(float);
  int* bg_idx      = (int*)w;            w += BB*MAXC*sizeof(int);
  float* bg_pri    = (float*)w;          w += BB*MAXC*sizeof(float);
  // total ~4.2 MB of d_ws

  k_prep<<<KAT/256, 256, 0, stream>>>(inside, inv, dN, abox, aar, keyf, keyb,
                                      fg_cnt, bg_cnt, (unsigned*)gt_max);
  k_gtmax<<<dim3(GG/GCH, ACH, BB), 256, 0, stream>>>(gt, abox, aar, dN, (unsigned*)gt_max);
  k_labels<<<dim3(NCAP/(256*ANPT), BB), 256, 0, stream>>>(gt, abox, aar, dN, gt_max,
                                                          keyf, keyb, lab, am,
                                                          fg_cnt, fg_idx, fg_pri,
                                                          bg_cnt, bg_idx, bg_pri);
  k_select<<<2*BB, 1024, 0, stream>>>(fg_cnt, fg_idx, fg_pri, bg_cnt, bg_idx, bg_pri, lab);
  k_out<<<dim3(KAT/256, BB), 256, 0, stream>>>(gt, inv, lab, am, out);
}